// Round 11
// baseline (254.775 us; speedup 1.0000x reference)
//
#include <hip/hip_runtime.h>
#include <stdint.h>
#include <stddef.h>

// Problem constants
#define B_N   4096
#define NSENT 64
#define DDIM  768
#define TOPK  5
#define FAN1  4608   // (TOPK+1)*768
#define H1DIM 1024
#define NCLS  4
#define KDIM  4608
#define KHALF 2304   // split-K=2: K per block

typedef __attribute__((ext_vector_type(8))) __bf16 bf16x8;
typedef __attribute__((ext_vector_type(4))) float  f32x4;

__device__ __forceinline__ unsigned short f2bf(float f) {
    unsigned int u = __float_as_uint(f);
    unsigned int r = (u + 0x7fffu + ((u >> 16) & 1u)) >> 16;
    return (unsigned short)r;
}

__device__ __forceinline__ void gl_lds16(const void* g, void* l) {
    __builtin_amdgcn_global_load_lds((__attribute__((address_space(1))) void*)(g),
                                     (__attribute__((address_space(3))) void*)(l),
                                     16, 0, 0);
}

// ---------------------------------------------------------------------------
// Kernel A: [fused W1 f32->bf16 prologue] + one-wave-per-row top-k gather.
// Prologue: block i converts W1 float4s [i*1152, (i+1)*1152) -> w1b (exact
// cover: 1024 x 1152 = 1179648), removing the separate conv launch.
// Dot phase (R10 post-mortem: memory duty cycle, not VALU, is the limiter):
// 2 rows per iteration (r0=8it+g, r1=r0+4), 24 independent loads in flight,
// 4 independent FMA chains (pa0/pa1/pb0/pb1) -> no full per-iteration drain.
// Then wave-local 5x butterfly argmax (strict >, tie -> lower index) and
// per-wave gather of 6 segments -> xx row (bf16). No __syncthreads at all.
// ---------------------------------------------------------------------------
__global__ __launch_bounds__(256, 4) void k_topk_gather(
    const float* __restrict__ sim_stance,
    const float* __restrict__ sim_body,
    const float* __restrict__ nli_stance,
    const float* __restrict__ nli_body,
    const float* __restrict__ W1,
    unsigned short* __restrict__ w1b,
    unsigned short* __restrict__ xx)
{
    const int tid  = threadIdx.x;
    const int lane = tid & 63;
    const int wave = tid >> 6;
    const int b    = blockIdx.x * 4 + wave;
    const int g    = lane >> 4;     // row-group 0..3
    const int c    = lane & 15;     // column slice
    __shared__ float sims_s[4][NSENT];

    // ---- fused W1 conversion: 1152 contiguous float4 per block ----
    {
        const int base = blockIdx.x * 1152;
        #pragma unroll
        for (int t = 0; t < 5; ++t) {           // 4.5 per thread -> 5 rounds
            const int i = base + t * 256 + tid;
            if (i < base + 1152) {
                float4 v = ((const float4*)W1)[i];
                ushort4 r;
                r.x = f2bf(v.x); r.y = f2bf(v.y); r.z = f2bf(v.z); r.w = f2bf(v.w);
                ((ushort4*)w1b)[i] = r;
            }
        }
    }

    // stance slice: float4 indices c + 16*j, j = 0..11 (48 floats/lane)
    const float4* st4 = (const float4*)(sim_stance + (size_t)b * DDIM);
    float4 st[12];
    #pragma unroll
    for (int j = 0; j < 12; ++j) st[j] = st4[c + 16 * j];

    const float* bodyb = sim_body + (size_t)b * NSENT * DDIM;
    #pragma unroll 1
    for (int it = 0; it < 8; ++it) {
        const int r0 = it * 8 + g;
        const int r1 = r0 + 4;
        const float4* ra = (const float4*)(bodyb + (size_t)r0 * DDIM);
        const float4* rb = (const float4*)(bodyb + (size_t)r1 * DDIM);
        float pa0 = 0.f, pa1 = 0.f, pb0 = 0.f, pb1 = 0.f;
        #pragma unroll
        for (int j = 0; j < 6; ++j) {
            float4 xa0 = ra[c + 16 * (2 * j)];
            float4 xa1 = ra[c + 16 * (2 * j + 1)];
            float4 xb0 = rb[c + 16 * (2 * j)];
            float4 xb1 = rb[c + 16 * (2 * j + 1)];
            const float4 s0 = st[2 * j], s1 = st[2 * j + 1];
            pa0 += xa0.x*s0.x + xa0.y*s0.y + xa0.z*s0.z + xa0.w*s0.w;
            pa1 += xa1.x*s1.x + xa1.y*s1.y + xa1.z*s1.z + xa1.w*s1.w;
            pb0 += xb0.x*s0.x + xb0.y*s0.y + xb0.z*s0.z + xb0.w*s0.w;
            pb1 += xb1.x*s1.x + xb1.y*s1.y + xb1.z*s1.z + xb1.w*s1.w;
        }
        float pa = pa0 + pa1, pb = pb0 + pb1;
        #pragma unroll
        for (int off = 8; off; off >>= 1) {
            pa += __shfl_xor(pa, off);
            pb += __shfl_xor(pb, off);
        }
        if (c == 0) { sims_s[wave][r0] = pa; sims_s[wave][r1] = pb; }
    }

    // wave-local argmax top-5 (compiler inserts lgkmcnt for the RAW)
    float v = sims_s[wave][lane];
    int topidx[TOPK];
    #pragma unroll
    for (int k = 0; k < TOPK; ++k) {
        float bv = v; int bi = lane;
        #pragma unroll
        for (int off = 32; off; off >>= 1) {
            float ov = __shfl_xor(bv, off);
            int   oi = __shfl_xor(bi, off);
            if (ov > bv || (ov == bv && oi < bi)) { bv = ov; bi = oi; }
        }
        topidx[k] = bi;                 // identical in all lanes
        if (lane == bi) v = -3.402823466e38f;
    }

    // gather + f32->bf16: 6 segments of 768 floats = 192 float4 each,
    // 3 float4 per lane per segment.
    unsigned short* xrow = xx + (size_t)b * FAN1;
    #pragma unroll
    for (int seg = 0; seg < 6; ++seg) {
        const float* src = (seg == 0)
            ? (nli_stance + (size_t)b * DDIM)
            : (nli_body + ((size_t)b * NSENT + topidx[seg - 1]) * DDIM);
        #pragma unroll
        for (int t = 0; t < 3; ++t) {
            const int i = t * 64 + lane;
            float4 vv = ((const float4*)src)[i];
            ushort4 o;
            o.x = f2bf(vv.x); o.y = f2bf(vv.y); o.z = f2bf(vv.z); o.w = f2bf(vv.w);
            ((ushort4*)(xrow + seg * DDIM))[i] = o;
        }
    }
}

// ---------------------------------------------------------------------------
// GEMM1 (split-K=2): P[ks][m][h] = sum_{k in half ks} xx[m][k]*W1[h][k]
// R8 structure (measured 40.7us ~ 950 TF via R9 replication): BM=BN=128,
// BK=64, 4 waves, wave tile 64x64, raw-barrier prefetch pipeline.
// ---------------------------------------------------------------------------
__global__ __launch_bounds__(256, 2) void k_gemm1(
    const unsigned short* __restrict__ A,   // xx bf16 [4096][4608]
    const unsigned short* __restrict__ W,   // W1 bf16 [1024][4608]
    float* __restrict__ P)                  // [2][4096][1024] f32 partials
{
    constexpr int BM = 128, BN = 128, BK = 64;
    constexpr int K = KDIM;
    __shared__ unsigned short lA[2][BM * BK];  // 2 x 16 KB
    __shared__ unsigned short lB[2][BN * BK];  // 2 x 16 KB

    const int tid = threadIdx.x, lane = tid & 63, wave = tid >> 6;
    const int bid = blockIdx.x;
    const int wk  = (bid & 7) * 64 + (bid >> 3);   // XCD-grouped work id
    const int ks  = wk >> 8;                       // K-half 0/1
    const int rem = wk & 255;
    const int bm  = rem >> 3, bn = rem & 7;
    const int wm = wave >> 1, wn = wave & 1;
    const int k0 = ks * KHALF;

    // ---- staging setup: 1024 chunks per side, 4 per thread (j=0..3) ----
    const int rowq = wave * 8 + (lane >> 3);
    const int sc   = (lane & 7) ^ (lane >> 3);  // swizzled global chunk
    const unsigned short* gA[4];
    const unsigned short* gB[4];
    #pragma unroll
    for (int j = 0; j < 4; ++j) {
        gA[j] = A + (size_t)(bm * BM + j * 32 + rowq) * K + k0 + sc * 8;
        gB[j] = W + (size_t)(bn * BN + j * 32 + rowq) * K + k0 + sc * 8;
    }
    const int ldsOff = (wave * 64) * 8;     // wave-uniform dest offset (elems)

    // ---- fragment read setup (swizzled) ----
    const int r16 = lane & 15;
    const int p0  = (lane >> 4) ^ (r16 & 7);   // slot for k-half 0 of BK
    const int p1  = p0 ^ 4;                    // slot for k-half 1 of BK
    const int aRowOff = (wm * 64 + r16) * BK;
    const int bRowOff = (wn * 64 + r16) * BK;

    f32x4 acc[4][4];
    #pragma unroll
    for (int m = 0; m < 4; ++m)
        #pragma unroll
        for (int n = 0; n < 4; ++n) acc[m][n] = {0.f, 0.f, 0.f, 0.f};

#define STAGE(SEL, T) do {                                                  \
    _Pragma("unroll")                                                       \
    for (int j = 0; j < 4; ++j)                                             \
        gl_lds16(gA[j] + (size_t)(T) * BK, &lA[SEL][j * 2048 + ldsOff]);    \
    _Pragma("unroll")                                                       \
    for (int j = 0; j < 4; ++j)                                             \
        gl_lds16(gB[j] + (size_t)(T) * BK, &lB[SEL][j * 2048 + ldsOff]);    \
} while (0)

#define COMPUTE(SEL) do {                                                   \
    bf16x8 fa[4][2], fb[4][2];                                              \
    _Pragma("unroll")                                                       \
    for (int m = 0; m < 4; ++m) {                                           \
        fa[m][0] = *(const bf16x8*)(&lA[SEL][aRowOff + m * 16 * BK + p0 * 8]); \
        fa[m][1] = *(const bf16x8*)(&lA[SEL][aRowOff + m * 16 * BK + p1 * 8]); \
    }                                                                       \
    _Pragma("unroll")                                                       \
    for (int n = 0; n < 4; ++n) {                                           \
        fb[n][0] = *(const bf16x8*)(&lB[SEL][bRowOff + n * 16 * BK + p0 * 8]); \
        fb[n][1] = *(const bf16x8*)(&lB[SEL][bRowOff + n * 16 * BK + p1 * 8]); \
    }                                                                       \
    _Pragma("unroll")                                                       \
    for (int h = 0; h < 2; ++h)                                             \
        _Pragma("unroll")                                                   \
        for (int m = 0; m < 4; ++m)                                         \
            _Pragma("unroll")                                               \
            for (int n = 0; n < 4; ++n)                                     \
                acc[m][n] = __builtin_amdgcn_mfma_f32_16x16x32_bf16(        \
                    fa[m][h], fb[n][h], acc[m][n], 0, 0, 0);                \
} while (0)

#define SYNCPIPE() asm volatile("s_waitcnt vmcnt(0)\n\ts_barrier" ::: "memory")

    STAGE(0, 0);
    SYNCPIPE();
    #pragma unroll 1
    for (int it = 0; it < 17; ++it) {
        const int t = 2 * it;
        STAGE(1, t + 1); COMPUTE(0); SYNCPIPE();
        STAGE(0, t + 2); COMPUTE(1); SYNCPIPE();
    }
    STAGE(1, 35); COMPUTE(0); SYNCPIPE();
    COMPUTE(1);

#undef STAGE
#undef COMPUTE
#undef SYNCPIPE

    // epilogue: C/D layout col=lane&15, row=(lane>>4)*4+reg; raw partials
    float* Pk = P + (size_t)ks * B_N * H1DIM;
    const int colbase = bn * BN + wn * 64 + r16;
    const int rowbase = bm * BM + wm * 64 + (lane >> 4) * 4;
    #pragma unroll
    for (int n = 0; n < 4; ++n) {
        const int col = colbase + n * 16;
        #pragma unroll
        for (int m = 0; m < 4; ++m) {
            const int row = rowbase + m * 16;
            #pragma unroll
            for (int j = 0; j < 4; ++j)
                Pk[(size_t)(row + j) * H1DIM + col] = acc[m][n][j];
        }
    }
}

// ---------------------------------------------------------------------------
// GEMM2 (+ fused split-K reduce, bias, relu):
// h[b][:] = relu(P0[b]+P1[b]+b1); out[b][c] = <h, W2[c]> + b2[c].
// ---------------------------------------------------------------------------
__global__ __launch_bounds__(256) void k_gemm2(
    const float* __restrict__ P, const float* __restrict__ W2,
    const float* __restrict__ b1, const float* __restrict__ b2,
    float* __restrict__ out)
{
    __shared__ float w2s[NCLS * H1DIM + H1DIM];
    const int tid = threadIdx.x, lane = tid & 63, wave = tid >> 6;
    const int row = blockIdx.x * 4 + wave;
    for (int i = tid; i < NCLS * H1DIM; i += 256) w2s[i] = W2[i];
    for (int i = tid; i < H1DIM; i += 256) w2s[NCLS * H1DIM + i] = b1[i];
    __syncthreads();

    const float4* p0 = (const float4*)(P + (size_t)row * H1DIM);
    const float4* p1 = (const float4*)(P + (size_t)(B_N + row) * H1DIM);
    const float4* w0 = (const float4*)&w2s[0];
    const float4* w1 = (const float4*)&w2s[H1DIM];
    const float4* w2 = (const float4*)&w2s[2 * H1DIM];
    const float4* w3 = (const float4*)&w2s[3 * H1DIM];
    const float4* bb = (const float4*)&w2s[4 * H1DIM];
    float a0 = 0.f, a1 = 0.f, a2 = 0.f, a3 = 0.f;
    #pragma unroll
    for (int j = 0; j < 4; ++j) {
        const int idx = j * 64 + lane;
        float4 x0 = p0[idx], x1 = p1[idx], bv = bb[idx];
        float4 h;
        h.x = x0.x + x1.x + bv.x; h.x = h.x > 0.f ? h.x : 0.f;
        h.y = x0.y + x1.y + bv.y; h.y = h.y > 0.f ? h.y : 0.f;
        h.z = x0.z + x1.z + bv.z; h.z = h.z > 0.f ? h.z : 0.f;
        h.w = x0.w + x1.w + bv.w; h.w = h.w > 0.f ? h.w : 0.f;
        float4 xv;
        xv = w0[idx]; a0 += h.x*xv.x + h.y*xv.y + h.z*xv.z + h.w*xv.w;
        xv = w1[idx]; a1 += h.x*xv.x + h.y*xv.y + h.z*xv.z + h.w*xv.w;
        xv = w2[idx]; a2 += h.x*xv.x + h.y*xv.y + h.z*xv.z + h.w*xv.w;
        xv = w3[idx]; a3 += h.x*xv.x + h.y*xv.y + h.z*xv.z + h.w*xv.w;
    }
    #pragma unroll
    for (int off = 32; off; off >>= 1) {
        a0 += __shfl_xor(a0, off);
        a1 += __shfl_xor(a1, off);
        a2 += __shfl_xor(a2, off);
        a3 += __shfl_xor(a3, off);
    }
    if (lane == 0) {
        float* o = out + (size_t)row * NCLS;
        o[0] = a0 + b2[0]; o[1] = a1 + b2[1]; o[2] = a2 + b2[2]; o[3] = a3 + b2[3];
    }
}

// ---------------------------------------------------------------------------
// Workspace layout (bytes; ws_size ~3.2 GB per poison-fill counters):
//   [0, 37748736)                 xx bf16          4096*4608*2
//   [37748736, 47185920)          W1 bf16          1024*4608*2
//   [47185920, 80740352)          P f32 partials   2*4096*1024*4
// ---------------------------------------------------------------------------
extern "C" void kernel_launch(void* const* d_in, const int* in_sizes, int n_in,
                              void* d_out, int out_size, void* d_ws, size_t ws_size,
                              hipStream_t stream)
{
    const float* sim_stance = (const float*)d_in[0];
    const float* nli_stance = (const float*)d_in[1];
    const float* sim_body   = (const float*)d_in[2];
    const float* nli_body   = (const float*)d_in[3];
    const float* W1 = (const float*)d_in[4];
    const float* b1 = (const float*)d_in[5];
    const float* W2 = (const float*)d_in[6];
    const float* b2 = (const float*)d_in[7];
    float* out = (float*)d_out;

    char* ws = (char*)d_ws;
    unsigned short* xx  = (unsigned short*)ws;
    unsigned short* w1b = (unsigned short*)(ws + 37748736u);
    float*          P   = (float*)(ws + 37748736u + 9437184u);

    k_topk_gather<<<dim3(1024), dim3(256), 0, stream>>>(sim_stance, sim_body,
                                                        nli_stance, nli_body,
                                                        W1, w1b, xx);
    k_gemm1<<<dim3(512), dim3(256), 0, stream>>>(xx, w1b, P);
    k_gemm2<<<dim3(1024), dim3(256), 0, stream>>>(P, W2, b1, b2, out);
}

// Round 12
// 241.368 us; speedup vs baseline: 1.0555x; 1.0555x over previous
//
#include <hip/hip_runtime.h>
#include <stdint.h>
#include <stddef.h>

// Problem constants
#define B_N   4096
#define NSENT 64
#define DDIM  768
#define TOPK  5
#define FAN1  4608   // (TOPK+1)*768
#define H1DIM 1024
#define NCLS  4
#define KDIM  4608
#define KHALF 2304   // split-K=2: K per block

typedef __attribute__((ext_vector_type(8))) __bf16 bf16x8;
typedef __attribute__((ext_vector_type(4))) float  f32x4;

__device__ __forceinline__ unsigned short f2bf(float f) {
    unsigned int u = __float_as_uint(f);
    unsigned int r = (u + 0x7fffu + ((u >> 16) & 1u)) >> 16;
    return (unsigned short)r;
}

__device__ __forceinline__ void gl_lds16(const void* g, void* l) {
    __builtin_amdgcn_global_load_lds((__attribute__((address_space(1))) void*)(g),
                                     (__attribute__((address_space(3))) void*)(l),
                                     16, 0, 0);
}

// ---------------------------------------------------------------------------
// Kernel A: one-wave-per-row top-k gather (exact R10 structure, best
// measured), with the W1 f32->bf16 conversion fused at the END (after the
// xx writes) — it fills tail bubbles instead of delaying the stream start
// (R11's prologue placement regressed).
// Per wave: 16 dot iterations (4 rows x 16-lane column slices, 4-shfl
// reduce); sims in wave-private LDS (no barriers anywhere); wave-local 5x
// butterfly argmax (strict >, tie -> lower index); gather 6 segments ->
// xx row (bf16). Then block-slice W1 conversion (1152 float4 per block).
// ---------------------------------------------------------------------------
__global__ __launch_bounds__(256, 4) void k_topk_gather(
    const float* __restrict__ sim_stance,
    const float* __restrict__ sim_body,
    const float* __restrict__ nli_stance,
    const float* __restrict__ nli_body,
    const float* __restrict__ W1,
    unsigned short* __restrict__ w1b,
    unsigned short* __restrict__ xx)
{
    const int tid  = threadIdx.x;
    const int lane = tid & 63;
    const int wave = tid >> 6;
    const int b    = blockIdx.x * 4 + wave;
    const int g    = lane >> 4;     // row-group 0..3
    const int c    = lane & 15;     // column slice
    __shared__ float sims_s[4][NSENT];

    // stance slice: float4 indices c + 16*j, j = 0..11 (48 floats/lane)
    const float4* st4 = (const float4*)(sim_stance + (size_t)b * DDIM);
    float4 st[12];
    #pragma unroll
    for (int j = 0; j < 12; ++j) st[j] = st4[c + 16 * j];

    const float* bodyb = sim_body + (size_t)b * NSENT * DDIM;
    #pragma unroll 1
    for (int it = 0; it < 16; ++it) {
        const int r = it * 4 + g;
        const float4* r4 = (const float4*)(bodyb + (size_t)r * DDIM);
        float p = 0.f;
        #pragma unroll
        for (int j = 0; j < 12; ++j) {
            float4 v = r4[c + 16 * j];
            p += v.x*st[j].x + v.y*st[j].y + v.z*st[j].z + v.w*st[j].w;
        }
        // reduce across the 16-lane group (xor stays within the group)
        #pragma unroll
        for (int off = 8; off; off >>= 1) p += __shfl_xor(p, off);
        if (c == 0) sims_s[wave][r] = p;
    }

    // wave-local argmax top-5 (compiler inserts lgkmcnt for the RAW)
    float v = sims_s[wave][lane];
    int topidx[TOPK];
    #pragma unroll
    for (int k = 0; k < TOPK; ++k) {
        float bv = v; int bi = lane;
        #pragma unroll
        for (int off = 32; off; off >>= 1) {
            float ov = __shfl_xor(bv, off);
            int   oi = __shfl_xor(bi, off);
            if (ov > bv || (ov == bv && oi < bi)) { bv = ov; bi = oi; }
        }
        topidx[k] = bi;                 // identical in all lanes
        if (lane == bi) v = -3.402823466e38f;
    }

    // gather + f32->bf16: 6 segments of 768 floats = 192 float4 each,
    // 3 float4 per lane per segment.
    unsigned short* xrow = xx + (size_t)b * FAN1;
    #pragma unroll
    for (int seg = 0; seg < 6; ++seg) {
        const float* src = (seg == 0)
            ? (nli_stance + (size_t)b * DDIM)
            : (nli_body + ((size_t)b * NSENT + topidx[seg - 1]) * DDIM);
        #pragma unroll
        for (int t = 0; t < 3; ++t) {
            const int i = t * 64 + lane;
            float4 vv = ((const float4*)src)[i];
            ushort4 o;
            o.x = f2bf(vv.x); o.y = f2bf(vv.y); o.z = f2bf(vv.z); o.w = f2bf(vv.w);
            ((ushort4*)(xrow + seg * DDIM))[i] = o;
        }
    }

    // ---- fused W1 conversion (tail): 1152 contiguous float4 per block ----
    {
        const int base = blockIdx.x * 1152;
        #pragma unroll
        for (int t = 0; t < 5; ++t) {           // 4.5 per thread -> 5 rounds
            const int i = base + t * 256 + tid;
            if (i < base + 1152) {
                float4 vv = ((const float4*)W1)[i];
                ushort4 r;
                r.x = f2bf(vv.x); r.y = f2bf(vv.y); r.z = f2bf(vv.z); r.w = f2bf(vv.w);
                ((ushort4*)w1b)[i] = r;
            }
        }
    }
}

// ---------------------------------------------------------------------------
// GEMM1 (split-K=2): P[ks][m][h] = sum_{k in half ks} xx[m][k]*W1[h][k]
// R8 structure (measured ~40.7us warm via R9 replication): BM=BN=128,
// BK=64, 4 waves, wave tile 64x64, raw-barrier prefetch pipeline.
// ---------------------------------------------------------------------------
__global__ __launch_bounds__(256, 2) void k_gemm1(
    const unsigned short* __restrict__ A,   // xx bf16 [4096][4608]
    const unsigned short* __restrict__ W,   // W1 bf16 [1024][4608]
    float* __restrict__ P)                  // [2][4096][1024] f32 partials
{
    constexpr int BM = 128, BN = 128, BK = 64;
    constexpr int K = KDIM;
    __shared__ unsigned short lA[2][BM * BK];  // 2 x 16 KB
    __shared__ unsigned short lB[2][BN * BK];  // 2 x 16 KB

    const int tid = threadIdx.x, lane = tid & 63, wave = tid >> 6;
    const int bid = blockIdx.x;
    const int wk  = (bid & 7) * 64 + (bid >> 3);   // XCD-grouped work id
    const int ks  = wk >> 8;                       // K-half 0/1
    const int rem = wk & 255;
    const int bm  = rem >> 3, bn = rem & 7;
    const int wm = wave >> 1, wn = wave & 1;
    const int k0 = ks * KHALF;

    // ---- staging setup: 1024 chunks per side, 4 per thread (j=0..3) ----
    const int rowq = wave * 8 + (lane >> 3);
    const int sc   = (lane & 7) ^ (lane >> 3);  // swizzled global chunk
    const unsigned short* gA[4];
    const unsigned short* gB[4];
    #pragma unroll
    for (int j = 0; j < 4; ++j) {
        gA[j] = A + (size_t)(bm * BM + j * 32 + rowq) * K + k0 + sc * 8;
        gB[j] = W + (size_t)(bn * BN + j * 32 + rowq) * K + k0 + sc * 8;
    }
    const int ldsOff = (wave * 64) * 8;     // wave-uniform dest offset (elems)

    // ---- fragment read setup (swizzled) ----
    const int r16 = lane & 15;
    const int p0  = (lane >> 4) ^ (r16 & 7);   // slot for k-half 0 of BK
    const int p1  = p0 ^ 4;                    // slot for k-half 1 of BK
    const int aRowOff = (wm * 64 + r16) * BK;
    const int bRowOff = (wn * 64 + r16) * BK;

    f32x4 acc[4][4];
    #pragma unroll
    for (int m = 0; m < 4; ++m)
        #pragma unroll
        for (int n = 0; n < 4; ++n) acc[m][n] = {0.f, 0.f, 0.f, 0.f};

#define STAGE(SEL, T) do {                                                  \
    _Pragma("unroll")                                                       \
    for (int j = 0; j < 4; ++j)                                             \
        gl_lds16(gA[j] + (size_t)(T) * BK, &lA[SEL][j * 2048 + ldsOff]);    \
    _Pragma("unroll")                                                       \
    for (int j = 0; j < 4; ++j)                                             \
        gl_lds16(gB[j] + (size_t)(T) * BK, &lB[SEL][j * 2048 + ldsOff]);    \
} while (0)

#define COMPUTE(SEL) do {                                                   \
    bf16x8 fa[4][2], fb[4][2];                                              \
    _Pragma("unroll")                                                       \
    for (int m = 0; m < 4; ++m) {                                           \
        fa[m][0] = *(const bf16x8*)(&lA[SEL][aRowOff + m * 16 * BK + p0 * 8]); \
        fa[m][1] = *(const bf16x8*)(&lA[SEL][aRowOff + m * 16 * BK + p1 * 8]); \
    }                                                                       \
    _Pragma("unroll")                                                       \
    for (int n = 0; n < 4; ++n) {                                           \
        fb[n][0] = *(const bf16x8*)(&lB[SEL][bRowOff + n * 16 * BK + p0 * 8]); \
        fb[n][1] = *(const bf16x8*)(&lB[SEL][bRowOff + n * 16 * BK + p1 * 8]); \
    }                                                                       \
    _Pragma("unroll")                                                       \
    for (int h = 0; h < 2; ++h)                                             \
        _Pragma("unroll")                                                   \
        for (int m = 0; m < 4; ++m)                                         \
            _Pragma("unroll")                                               \
            for (int n = 0; n < 4; ++n)                                     \
                acc[m][n] = __builtin_amdgcn_mfma_f32_16x16x32_bf16(        \
                    fa[m][h], fb[n][h], acc[m][n], 0, 0, 0);                \
} while (0)

#define SYNCPIPE() asm volatile("s_waitcnt vmcnt(0)\n\ts_barrier" ::: "memory")

    STAGE(0, 0);
    SYNCPIPE();
    #pragma unroll 1
    for (int it = 0; it < 17; ++it) {
        const int t = 2 * it;
        STAGE(1, t + 1); COMPUTE(0); SYNCPIPE();
        STAGE(0, t + 2); COMPUTE(1); SYNCPIPE();
    }
    STAGE(1, 35); COMPUTE(0); SYNCPIPE();
    COMPUTE(1);

#undef STAGE
#undef COMPUTE
#undef SYNCPIPE

    // epilogue: C/D layout col=lane&15, row=(lane>>4)*4+reg; raw partials
    float* Pk = P + (size_t)ks * B_N * H1DIM;
    const int colbase = bn * BN + wn * 64 + r16;
    const int rowbase = bm * BM + wm * 64 + (lane >> 4) * 4;
    #pragma unroll
    for (int n = 0; n < 4; ++n) {
        const int col = colbase + n * 16;
        #pragma unroll
        for (int m = 0; m < 4; ++m) {
            const int row = rowbase + m * 16;
            #pragma unroll
            for (int j = 0; j < 4; ++j)
                Pk[(size_t)(row + j) * H1DIM + col] = acc[m][n][j];
        }
    }
}

// ---------------------------------------------------------------------------
// GEMM2 (+ fused split-K reduce, bias, relu):
// h[b][:] = relu(P0[b]+P1[b]+b1); out[b][c] = <h, W2[c]> + b2[c].
// ---------------------------------------------------------------------------
__global__ __launch_bounds__(256) void k_gemm2(
    const float* __restrict__ P, const float* __restrict__ W2,
    const float* __restrict__ b1, const float* __restrict__ b2,
    float* __restrict__ out)
{
    __shared__ float w2s[NCLS * H1DIM + H1DIM];
    const int tid = threadIdx.x, lane = tid & 63, wave = tid >> 6;
    const int row = blockIdx.x * 4 + wave;
    for (int i = tid; i < NCLS * H1DIM; i += 256) w2s[i] = W2[i];
    for (int i = tid; i < H1DIM; i += 256) w2s[NCLS * H1DIM + i] = b1[i];
    __syncthreads();

    const float4* p0 = (const float4*)(P + (size_t)row * H1DIM);
    const float4* p1 = (const float4*)(P + (size_t)(B_N + row) * H1DIM);
    const float4* w0 = (const float4*)&w2s[0];
    const float4* w1 = (const float4*)&w2s[H1DIM];
    const float4* w2 = (const float4*)&w2s[2 * H1DIM];
    const float4* w3 = (const float4*)&w2s[3 * H1DIM];
    const float4* bb = (const float4*)&w2s[4 * H1DIM];
    float a0 = 0.f, a1 = 0.f, a2 = 0.f, a3 = 0.f;
    #pragma unroll
    for (int j = 0; j < 4; ++j) {
        const int idx = j * 64 + lane;
        float4 x0 = p0[idx], x1 = p1[idx], bv = bb[idx];
        float4 h;
        h.x = x0.x + x1.x + bv.x; h.x = h.x > 0.f ? h.x : 0.f;
        h.y = x0.y + x1.y + bv.y; h.y = h.y > 0.f ? h.y : 0.f;
        h.z = x0.z + x1.z + bv.z; h.z = h.z > 0.f ? h.z : 0.f;
        h.w = x0.w + x1.w + bv.w; h.w = h.w > 0.f ? h.w : 0.f;
        float4 xv;
        xv = w0[idx]; a0 += h.x*xv.x + h.y*xv.y + h.z*xv.z + h.w*xv.w;
        xv = w1[idx]; a1 += h.x*xv.x + h.y*xv.y + h.z*xv.z + h.w*xv.w;
        xv = w2[idx]; a2 += h.x*xv.x + h.y*xv.y + h.z*xv.z + h.w*xv.w;
        xv = w3[idx]; a3 += h.x*xv.x + h.y*xv.y + h.z*xv.z + h.w*xv.w;
    }
    #pragma unroll
    for (int off = 32; off; off >>= 1) {
        a0 += __shfl_xor(a0, off);
        a1 += __shfl_xor(a1, off);
        a2 += __shfl_xor(a2, off);
        a3 += __shfl_xor(a3, off);
    }
    if (lane == 0) {
        float* o = out + (size_t)row * NCLS;
        o[0] = a0 + b2[0]; o[1] = a1 + b2[1]; o[2] = a2 + b2[2]; o[3] = a3 + b2[3];
    }
}

// ---------------------------------------------------------------------------
// Workspace layout (bytes; ws_size ~3.2 GB per poison-fill counters):
//   [0, 37748736)                 xx bf16          4096*4608*2
//   [37748736, 47185920)          W1 bf16          1024*4608*2
//   [47185920, 80740352)          P f32 partials   2*4096*1024*4
// ---------------------------------------------------------------------------
extern "C" void kernel_launch(void* const* d_in, const int* in_sizes, int n_in,
                              void* d_out, int out_size, void* d_ws, size_t ws_size,
                              hipStream_t stream)
{
    const float* sim_stance = (const float*)d_in[0];
    const float* nli_stance = (const float*)d_in[1];
    const float* sim_body   = (const float*)d_in[2];
    const float* nli_body   = (const float*)d_in[3];
    const float* W1 = (const float*)d_in[4];
    const float* b1 = (const float*)d_in[5];
    const float* W2 = (const float*)d_in[6];
    const float* b2 = (const float*)d_in[7];
    float* out = (float*)d_out;

    char* ws = (char*)d_ws;
    unsigned short* xx  = (unsigned short*)ws;
    unsigned short* w1b = (unsigned short*)(ws + 37748736u);
    float*          P   = (float*)(ws + 37748736u + 9437184u);

    k_topk_gather<<<dim3(1024), dim3(256), 0, stream>>>(sim_stance, sim_body,
                                                        nli_stance, nli_body,
                                                        W1, w1b, xx);
    k_gemm1<<<dim3(512), dim3(256), 0, stream>>>(xx, w1b, P);
    k_gemm2<<<dim3(1024), dim3(256), 0, stream>>>(P, W2, b1, b2, out);
}